// Round 12
// baseline (112.106 us; speedup 1.0000x reference)
//
#include <hip/hip_runtime.h>

// ---------------------------------------------------------------------------
// STRODE fused kernel for MI355X (gfx950) — round 11 (resubmit; infra flake)
// r9 base + wave specialization on 16x16x32 ONLY (r10's 32x32x16 reverted —
// prime NaN suspect; its A/B fragment layout was never validated here).
//   A-waves (0-3): S1, two u-tiles each, full K=512, w1r[32]=128 regs.
//   B-waves (4-7): S3, eight d-tiles each, w3r[32]=128 regs + fp32 Yr[8][2].
//   All waves:     S2 swapped (A=W2 regs rows u', B=H1 LDS) -> contiguous
//                  b64 H2 stores (b16 scatters deleted), no W2s staging.
// Bias folds (verified 16x16 layouts only):
//   H1[*][127]=1.0  + W2b[u'][127]=b2[u'] => b2 inside S2 MFMA
//   H2[b][127]=dt[b] + W3b[d][127]=b3[d]  => b3*dt inside S3 MFMA
// ---------------------------------------------------------------------------

typedef __attribute__((ext_vector_type(8))) short s16x8;   // 8 x bf16 frag
typedef __attribute__((ext_vector_type(4))) float fx4;     // MFMA acc

#define NB 8192
#define DD 512
#define UU 100
#define UP 128

__device__ __forceinline__ unsigned int f2bf(float x) {
  unsigned int u = __float_as_uint(x);
  return (u + 0x7FFFu + ((u >> 16) & 1u)) >> 16;   // RNE (prep only)
}
__device__ __forceinline__ float bf2f(unsigned int h) {
  return __uint_as_float(h << 16);
}
__device__ __forceinline__ unsigned int cvt_pk_bf16(float lo, float hi) {
  unsigned int r;
  asm("v_cvt_pk_bf16_f32 %0, %1, %2" : "=v"(r) : "v"(lo), "v"(hi));
  return r;
}
__device__ __forceinline__ float tanh5(float x) {
  float e = __builtin_amdgcn_exp2f(x * 2.885390081777927f);
  return 1.0f - 2.0f / (e + 1.0f);
}

// ---------------------------------------------------------------------------
// Weight prep: fp32 -> bf16, pad U=100 -> 128 with zeros.
//   W2b col 127 = b2 (pairs with H1[*][127]=1.0)
//   W3b col 127 = b3 (pairs with H2[b][127]=dt[b])
// ---------------------------------------------------------------------------
__global__ void prep_weights(const float* __restrict__ W1,
                             const float* __restrict__ W2,
                             const float* __restrict__ W3,
                             const float* __restrict__ b2,
                             const float* __restrict__ b3,
                             unsigned short* __restrict__ ws) {
  int e = blockIdx.x * 256 + threadIdx.x;
  if (e < 65536) {                        // W1b[128][512]
    int u = e >> 9, kc = e & 511;
    ws[e] = (u < UU) ? (unsigned short)f2bf(W1[u * DD + kc]) : (unsigned short)0;
  } else if (e < 81920) {                 // W2b[128][128]
    int e2 = e - 65536;
    int n = e2 >> 7, kc = e2 & 127;
    unsigned short v = 0;
    if (kc == 127)      v = (n < UU) ? (unsigned short)f2bf(b2[n]) : (unsigned short)0;
    else if (n < UU && kc < UU) v = (unsigned short)f2bf(W2[n * UU + kc]);
    ws[e] = v;
  } else if (e < 147456) {                // W3b[512][128]
    int e3 = e - 81920;
    int d = e3 >> 7, kc = e3 & 127;
    unsigned short v = 0;
    if (kc == 127)      v = (unsigned short)f2bf(b3[d]);
    else if (kc < UU)   v = (unsigned short)f2bf(W3[d * UU + kc]);
    ws[e] = v;
  }
}

// ---------------------------------------------------------------------------
// Main fused ODE kernel. grid = 256 WGs x 512 thr (8 waves), 32 rows/WG.
// ---------------------------------------------------------------------------
__global__ __launch_bounds__(512) __attribute__((amdgpu_waves_per_eu(2, 2)))
void ode_main(
    const float* __restrict__ y0, const float* __restrict__ t_seq,
    const float* __restrict__ b1,
    const unsigned short* __restrict__ W1b,
    const unsigned short* __restrict__ W2b,
    const unsigned short* __restrict__ W3b,
    const int* __restrict__ kptr, float* __restrict__ out) {
  __shared__ char Yb[32 * DD * 2];   // 32 KB bf16 Y [32][512], swizzled
  __shared__ char H1[32 * UP * 2];   //  8 KB bf16 H1 [32][128]; col 127 = 1.0
  __shared__ char H2[32 * UP * 2];   //  8 KB bf16 H2 [32][128]; col 127 = dt

  const int tid  = threadIdx.x;
  const int w    = tid >> 6;         // wave 0..7 (A: 0-3 -> S1, B: 4-7 -> S3)
  const int lane = tid & 63;
  const int lo   = lane & 15;
  const int hi   = lane >> 4;
  const int wb   = w - 4;            // B-wave index
  const int b0   = blockIdx.x * 32;
  const int k    = *kptr;
  const float kinv = 1.0f / (float)k;

  auto ybo = [](int b, int byr) -> int { return (b << 10) + (byr ^ ((b & 7) << 4)); };
  auto ho  = [](int b, int byr) -> int { return (b << 8)  + (byr ^ ((b & 7) << 4)); };

  // ---- per-wave register-resident weights (128 regs, divergent role) ----
  s16x8 wr[32];
  float b1v[2][4];                   // A-waves only
  if (w < 4) {
    // W1 16x16x32 A-frags: tiles t = 2w+i, row u = t*16+lo, k = kk*32+hi*8
#pragma unroll
    for (int i = 0; i < 2; ++i)
#pragma unroll
      for (int kk = 0; kk < 16; ++kk)
        wr[i * 16 + kk] =
            *(const s16x8*)(W1b + ((2 * w + i) * 16 + lo) * DD + kk * 32 + hi * 8);
#pragma unroll
    for (int i = 0; i < 2; ++i)
#pragma unroll
      for (int r = 0; r < 4; ++r) {
        int u = (2 * w + i) * 16 + hi * 4 + r;
        b1v[i][r] = (u < UU) ? b1[u] : 0.0f;
      }
  } else {
    // W3 16x16x32 A-frags: tiles t = wb*8+i, row d = t*16+lo, k = kk*32+hi*8
#pragma unroll
    for (int i = 0; i < 8; ++i)
#pragma unroll
      for (int kk = 0; kk < 4; ++kk)
        wr[i * 4 + kk] =
            *(const s16x8*)(W3b + ((wb * 8 + i) * 16 + lo) * UP + kk * 32 + hi * 8);
  }
  s16x8 w2r[4];                      // all waves: W2 row u' = w*16+lo
#pragma unroll
  for (int kk = 0; kk < 4; ++kk)
    w2r[kk] = *(const s16x8*)(W2b + (w * 16 + lo) * UP + kk * 32 + hi * 8);
  float dt2[2];                      // dt for b = j*16+lo
#pragma unroll
  for (int j = 0; j < 2; ++j) {
    int b = b0 + j * 16 + lo;
    dt2[j] = (t_seq[2 * b + 1] - t_seq[2 * b]) * kinv;
  }

  // ---- persistent Y (B-waves): Yr[i][j][r] = Y[b=j*16+lo][d=(wb*8+i)*16+hi*4+r]
  fx4 Yr[8][2];
  if (w >= 4) {
#pragma unroll
    for (int i = 0; i < 8; ++i)
#pragma unroll
      for (int j = 0; j < 2; ++j) {
        const float* p =
            y0 + (size_t)(b0 + j * 16 + lo) * DD + (wb * 8 + i) * 16 + hi * 4;
        Yr[i][j] = *(const fx4*)p;
      }
  }

  auto write_yb = [&]() {            // B-waves only
#pragma unroll
    for (int i = 0; i < 8; ++i)
#pragma unroll
      for (int j = 0; j < 2; ++j) {
        uint2 q;
        q.x = cvt_pk_bf16(Yr[i][j][0], Yr[i][j][1]);
        q.y = cvt_pk_bf16(Yr[i][j][2], Yr[i][j][3]);
        *(uint2*)(Yb + ybo(j * 16 + lo, ((wb * 8 + i) * 16 + hi * 4) * 2)) = q;
      }
  };
  if (w >= 4) write_yb();
  __syncthreads();

  const fx4 zf = {0.f, 0.f, 0.f, 0.f};

#pragma unroll 1
  for (int s = 0; s < k; ++s) {
    // ===== S1 (A-waves): H1[b][u] = tanh(W1 Y^T + b1); H1[*][127] = 1.0 ===
    if (w < 4) {
      fx4 acc[2][2];
#pragma unroll
      for (int i = 0; i < 2; ++i)
#pragma unroll
        for (int j = 0; j < 2; ++j)
#pragma unroll
          for (int r = 0; r < 4; ++r) acc[i][j][r] = b1v[i][r];
      __builtin_amdgcn_s_setprio(1);
#pragma unroll
      for (int kk = 0; kk < 16; ++kk) {
        int bro = kk * 64 + hi * 16;
        s16x8 bb0 = *(const s16x8*)(Yb + ybo(lo, bro));
        s16x8 bb1 = *(const s16x8*)(Yb + ybo(16 + lo, bro));
        acc[0][0] = __builtin_amdgcn_mfma_f32_16x16x32_bf16(wr[kk], bb0, acc[0][0], 0, 0, 0);
        acc[0][1] = __builtin_amdgcn_mfma_f32_16x16x32_bf16(wr[kk], bb1, acc[0][1], 0, 0, 0);
        acc[1][0] = __builtin_amdgcn_mfma_f32_16x16x32_bf16(wr[16 + kk], bb0, acc[1][0], 0, 0, 0);
        acc[1][1] = __builtin_amdgcn_mfma_f32_16x16x32_bf16(wr[16 + kk], bb1, acc[1][1], 0, 0, 0);
      }
      __builtin_amdgcn_s_setprio(0);
#pragma unroll
      for (int i = 0; i < 2; ++i)
#pragma unroll
        for (int j = 0; j < 2; ++j) {
          float v0 = tanh5(acc[i][j][0]);
          float v1 = tanh5(acc[i][j][1]);
          float v2 = tanh5(acc[i][j][2]);
          float v3 = tanh5(acc[i][j][3]);
          if (w == 3 && i == 1 && hi == 3) v3 = 1.0f;   // u = 127
          uint2 q;
          q.x = cvt_pk_bf16(v0, v1);
          q.y = cvt_pk_bf16(v2, v3);
          *(uint2*)(H1 + ho(j * 16 + lo, ((2 * w + i) * 16 + hi * 4) * 2)) = q;
        }
    }
    __syncthreads();

    // ===== S2 (all, swapped): H2[b][u'] = tanh(W2 H1^T)*dt; H2[b][127]=dt ==
    {
      fx4 c2[2];
      c2[0] = zf; c2[1] = zf;
      __builtin_amdgcn_s_setprio(1);
#pragma unroll
      for (int kk = 0; kk < 4; ++kk) {
        int bro = kk * 64 + hi * 16;
        s16x8 hb0 = *(const s16x8*)(H1 + ho(lo, bro));
        s16x8 hb1 = *(const s16x8*)(H1 + ho(16 + lo, bro));
        c2[0] = __builtin_amdgcn_mfma_f32_16x16x32_bf16(w2r[kk], hb0, c2[0], 0, 0, 0);
        c2[1] = __builtin_amdgcn_mfma_f32_16x16x32_bf16(w2r[kk], hb1, c2[1], 0, 0, 0);
      }
      __builtin_amdgcn_s_setprio(0);
#pragma unroll
      for (int j = 0; j < 2; ++j) {
        float h0 = tanh5(c2[j][0]) * dt2[j];
        float h1x = tanh5(c2[j][1]) * dt2[j];
        float h2x = tanh5(c2[j][2]) * dt2[j];
        float h3 = tanh5(c2[j][3]) * dt2[j];
        if (w == 7 && hi == 3) h3 = dt2[j];             // u' = 127
        uint2 q;
        q.x = cvt_pk_bf16(h0, h1x);
        q.y = cvt_pk_bf16(h2x, h3);
        *(uint2*)(H2 + ho(j * 16 + lo, (w * 16 + hi * 4) * 2)) = q;
      }
    }
    __syncthreads();

    // ===== S3 (B-waves): Yr += W3 H2^T  (b3*dt via col 127) ===============
    if (w >= 4) {
      __builtin_amdgcn_s_setprio(1);
#pragma unroll
      for (int kk = 0; kk < 4; ++kk) {
        int bro = kk * 64 + hi * 16;
        s16x8 bb0 = *(const s16x8*)(H2 + ho(lo, bro));
        s16x8 bb1 = *(const s16x8*)(H2 + ho(16 + lo, bro));
#pragma unroll
        for (int i = 0; i < 8; ++i) {
          Yr[i][0] = __builtin_amdgcn_mfma_f32_16x16x32_bf16(wr[i * 4 + kk], bb0, Yr[i][0], 0, 0, 0);
          Yr[i][1] = __builtin_amdgcn_mfma_f32_16x16x32_bf16(wr[i * 4 + kk], bb1, Yr[i][1], 0, 0, 0);
        }
      }
      __builtin_amdgcn_s_setprio(0);
      write_yb();
    }
    __syncthreads();
  }

  // ---- final store: coalesced fp32 from bf16 Yb -------------------------
  for (int idx = tid; idx < 32 * DD; idx += 512) {
    int b = idx >> 9, d = idx & 511;
    unsigned short hx = *(const unsigned short*)(Yb + ybo(b, 2 * d));
    out[(size_t)(b0 + b) * 513 + d] = bf2f((unsigned int)hx);
  }
}

// ---------------------------------------------------------------------------
// Loss column:  loss = ycum[-2] = 0.01 * sum_{t=1..98} gm_t   (exact algebra)
// ---------------------------------------------------------------------------
__global__ void loss_kernel(const float* __restrict__ bdp,
                            const float* __restrict__ sp,
                            const float* __restrict__ sdp,
                            float* __restrict__ out) {
  int b = blockIdx.x * 256 + threadIdx.x;
  if (b >= NB) return;
  float bd = bdp[b];
  float Kv = sp[b] + __logf(-bd + 0.01f) - __logf(sdp[b] + 0.01f);
  float acc = 0.0f;
  for (int t = 1; t <= 98; ++t) {
    float m = 0.01f * (float)t - 1.0f;     // in (-1, 0)
    float L = __logf(-m);                  // negative
    acc += (-bd) / (m * L) * (Kv - __logf(-L));
  }
  out[(size_t)b * 513 + 512] = 0.01f * acc;
}

// ---------------------------------------------------------------------------
extern "C" void kernel_launch(void* const* d_in, const int* in_sizes, int n_in,
                              void* d_out, int out_size, void* d_ws, size_t ws_size,
                              hipStream_t stream) {
  const float* y0    = (const float*)d_in[0];
  const float* t_seq = (const float*)d_in[1];
  const float* W1    = (const float*)d_in[2];
  const float* b1    = (const float*)d_in[3];
  const float* W2    = (const float*)d_in[4];
  const float* b2    = (const float*)d_in[5];
  const float* W3    = (const float*)d_in[6];
  const float* b3    = (const float*)d_in[7];
  const float* bd    = (const float*)d_in[9];
  const float* s_    = (const float*)d_in[10];
  const float* sd    = (const float*)d_in[11];
  const int*   kptr  = (const int*)d_in[12];
  float* out = (float*)d_out;
  unsigned short* ws = (unsigned short*)d_ws;

  prep_weights<<<576, 256, 0, stream>>>(W1, W2, W3, b2, b3, ws);
  ode_main<<<256, 512, 0, stream>>>(y0, t_seq, b1,
                                    ws, ws + 65536, ws + 81920, kptr, out);
  loss_kernel<<<32, 256, 0, stream>>>(bd, s_, sd, out);
}

// Round 13
// 94.265 us; speedup vs baseline: 1.1893x; 1.1893x over previous
//
#include <hip/hip_runtime.h>

// ---------------------------------------------------------------------------
// STRODE fused kernel for MI355X (gfx950) — round 13
// r9 base (91.6 us best; all 8 waves active in every phase — r12 proved
// wave-specialization idles the SIMD partner and loses 10%) + r12's verified
// S2-swap and bias-fold tricks:
//   S1: H1[b][u-tile w] = tanh(W1 Y^T + b1-init)        w1r[16] regs
//   S2 swapped: H2[b][u'-tile w] = tanh(W2 H1^T)*dt     w2r[4] regs,
//       contiguous b64 stores (b16 scatters deleted), no W2s LDS
//   S3: Yr += W3 H2^T                                    w3r[4][4] regs
// Folds: H1[*][127]=1.0 (x W2b[u'][127]=b2) ; H2[b][127]=dt[b]
//        (x W3b[d][127]=b3) -> b2 and b3*dt inside the MFMAs.
// ---------------------------------------------------------------------------

typedef __attribute__((ext_vector_type(8))) short s16x8;   // 8 x bf16 frag
typedef __attribute__((ext_vector_type(4))) float fx4;     // MFMA acc

#define NB 8192
#define DD 512
#define UU 100
#define UP 128
#define BM 32

__device__ __forceinline__ unsigned int f2bf(float x) {
  unsigned int u = __float_as_uint(x);
  return (u + 0x7FFFu + ((u >> 16) & 1u)) >> 16;   // RNE (prep only)
}
__device__ __forceinline__ float bf2f(unsigned int h) {
  return __uint_as_float(h << 16);
}
__device__ __forceinline__ unsigned int cvt_pk_bf16(float lo, float hi) {
  unsigned int r;
  asm("v_cvt_pk_bf16_f32 %0, %1, %2" : "=v"(r) : "v"(lo), "v"(hi));
  return r;
}
__device__ __forceinline__ float tanh5(float x) {
  float e = __builtin_amdgcn_exp2f(x * 2.885390081777927f);
  return 1.0f - 2.0f / (e + 1.0f);
}

// ---------------------------------------------------------------------------
// Weight prep: fp32 -> bf16, pad U=100 -> 128 with zeros.
//   W2b col 127 = b2 (pairs with H1[*][127]=1.0)
//   W3b col 127 = b3 (pairs with H2[b][127]=dt[b])
// ---------------------------------------------------------------------------
__global__ void prep_weights(const float* __restrict__ W1,
                             const float* __restrict__ W2,
                             const float* __restrict__ W3,
                             const float* __restrict__ b2,
                             const float* __restrict__ b3,
                             unsigned short* __restrict__ ws) {
  int e = blockIdx.x * 256 + threadIdx.x;
  if (e < 65536) {                        // W1b[128][512]
    int u = e >> 9, kc = e & 511;
    ws[e] = (u < UU) ? (unsigned short)f2bf(W1[u * DD + kc]) : (unsigned short)0;
  } else if (e < 81920) {                 // W2b[128][128]
    int e2 = e - 65536;
    int n = e2 >> 7, kc = e2 & 127;
    unsigned short v = 0;
    if (kc == 127)      v = (n < UU) ? (unsigned short)f2bf(b2[n]) : (unsigned short)0;
    else if (n < UU && kc < UU) v = (unsigned short)f2bf(W2[n * UU + kc]);
    ws[e] = v;
  } else if (e < 147456) {                // W3b[512][128]
    int e3 = e - 81920;
    int d = e3 >> 7, kc = e3 & 127;
    unsigned short v = 0;
    if (kc == 127)      v = (unsigned short)f2bf(b3[d]);
    else if (kc < UU)   v = (unsigned short)f2bf(W3[d * UU + kc]);
    ws[e] = v;
  }
}

// ---------------------------------------------------------------------------
// Main fused ODE kernel. grid = 256 WGs x 512 thr (8 waves), 32 rows/WG.
// ---------------------------------------------------------------------------
__global__ __launch_bounds__(512) __attribute__((amdgpu_waves_per_eu(2, 2)))
void ode_main(
    const float* __restrict__ y0, const float* __restrict__ t_seq,
    const float* __restrict__ b1,
    const unsigned short* __restrict__ W1b,
    const unsigned short* __restrict__ W2b,
    const unsigned short* __restrict__ W3b,
    const int* __restrict__ kptr, float* __restrict__ out) {
  __shared__ char Yb[BM * DD * 2];   // 32 KB bf16 Y [32][512], swizzled
  __shared__ char H1[BM * UP * 2];   //  8 KB bf16 H1 [32][128]; col 127 = 1.0
  __shared__ char H2[BM * UP * 2];   //  8 KB bf16 H2 [32][128]; col 127 = dt

  const int tid  = threadIdx.x;
  const int w    = tid >> 6;         // wave 0..7
  const int lane = tid & 63;
  const int lo   = lane & 15;
  const int hi   = lane >> 4;
  const int b0   = blockIdx.x * BM;
  const int k    = *kptr;
  const float kinv = 1.0f / (float)k;

  auto ybo = [](int b, int byr) -> int { return (b << 10) + (byr ^ ((b & 7) << 4)); };
  auto ho  = [](int b, int byr) -> int { return (b << 8)  + (byr ^ ((b & 7) << 4)); };

  // ---- register-resident weights ----------------------------------------
  s16x8 w1r[16];                     // W1[u=16w+lo][K=512]  64 regs
#pragma unroll
  for (int kk = 0; kk < 16; ++kk)
    w1r[kk] = *(const s16x8*)(W1b + (16 * w + lo) * DD + kk * 32 + hi * 8);
  s16x8 w2r[4];                      // W2[u'=16w+lo][K=128] 16 regs
#pragma unroll
  for (int kk = 0; kk < 4; ++kk)
    w2r[kk] = *(const s16x8*)(W2b + (16 * w + lo) * UP + kk * 32 + hi * 8);
  s16x8 w3r[4][4];                   // W3[d=(4w+i)*16+lo][K=128] 64 regs
#pragma unroll
  for (int i = 0; i < 4; ++i)
#pragma unroll
    for (int kk = 0; kk < 4; ++kk)
      w3r[i][kk] = *(const s16x8*)(W3b + ((4 * w + i) * 16 + lo) * UP + kk * 32 + hi * 8);

  // ---- hoisted per-thread constants -------------------------------------
  float b1v[4];                      // u = 16w + 4hi + r
#pragma unroll
  for (int r = 0; r < 4; ++r) {
    int u = 16 * w + 4 * hi + r;
    b1v[r] = (u < UU) ? b1[u] : 0.0f;
  }
  float dt2[2];                      // dt for b = j*16+lo
#pragma unroll
  for (int j = 0; j < 2; ++j) {
    int b = b0 + j * 16 + lo;
    dt2[j] = (t_seq[2 * b + 1] - t_seq[2 * b]) * kinv;
  }

  // ---- persistent Y: Yr[i][j][r] = Y[b=j*16+lo][d=(4w+i)*16+hi*4+r] ------
  fx4 Yr[4][2];
#pragma unroll
  for (int i = 0; i < 4; ++i)
#pragma unroll
    for (int j = 0; j < 2; ++j) {
      const float* p = y0 + (size_t)(b0 + j * 16 + lo) * DD + (4 * w + i) * 16 + hi * 4;
      Yr[i][j] = *(const fx4*)p;
    }

  auto write_yb = [&]() {
#pragma unroll
    for (int i = 0; i < 4; ++i)
#pragma unroll
      for (int j = 0; j < 2; ++j) {
        uint2 q;
        q.x = cvt_pk_bf16(Yr[i][j][0], Yr[i][j][1]);
        q.y = cvt_pk_bf16(Yr[i][j][2], Yr[i][j][3]);
        *(uint2*)(Yb + ybo(j * 16 + lo, ((4 * w + i) * 16 + hi * 4) * 2)) = q;
      }
  };
  write_yb();
  __syncthreads();

  const fx4 zf = {0.f, 0.f, 0.f, 0.f};

#pragma unroll 1
  for (int s = 0; s < k; ++s) {
    // ===== S1: H1[b][u-tile w] = tanh(W1 Y^T + b1); H1[*][127] = 1.0 ======
    {
      fx4 aA[2], aB[2];
#pragma unroll
      for (int j = 0; j < 2; ++j)
#pragma unroll
        for (int r = 0; r < 4; ++r) { aA[j][r] = b1v[r]; aB[j][r] = 0.0f; }
      __builtin_amdgcn_s_setprio(1);
#pragma unroll
      for (int kk = 0; kk < 16; kk += 2) {
        int bro0 = kk * 64 + hi * 16;
        int bro1 = (kk + 1) * 64 + hi * 16;
        s16x8 b00 = *(const s16x8*)(Yb + ybo(lo, bro0));
        s16x8 b01 = *(const s16x8*)(Yb + ybo(16 + lo, bro0));
        s16x8 b10 = *(const s16x8*)(Yb + ybo(lo, bro1));
        s16x8 b11 = *(const s16x8*)(Yb + ybo(16 + lo, bro1));
        aA[0] = __builtin_amdgcn_mfma_f32_16x16x32_bf16(w1r[kk], b00, aA[0], 0, 0, 0);
        aA[1] = __builtin_amdgcn_mfma_f32_16x16x32_bf16(w1r[kk], b01, aA[1], 0, 0, 0);
        aB[0] = __builtin_amdgcn_mfma_f32_16x16x32_bf16(w1r[kk + 1], b10, aB[0], 0, 0, 0);
        aB[1] = __builtin_amdgcn_mfma_f32_16x16x32_bf16(w1r[kk + 1], b11, aB[1], 0, 0, 0);
      }
      __builtin_amdgcn_s_setprio(0);
#pragma unroll
      for (int j = 0; j < 2; ++j) {
        float v0 = tanh5(aA[j][0] + aB[j][0]);
        float v1 = tanh5(aA[j][1] + aB[j][1]);
        float v2 = tanh5(aA[j][2] + aB[j][2]);
        float v3 = tanh5(aA[j][3] + aB[j][3]);
        if (w == 7 && hi == 3) v3 = 1.0f;          // u = 127 slot
        uint2 q;
        q.x = cvt_pk_bf16(v0, v1);
        q.y = cvt_pk_bf16(v2, v3);
        *(uint2*)(H1 + ho(j * 16 + lo, (16 * w + 4 * hi) * 2)) = q;
      }
    }
    __syncthreads();

    // ===== S2 swapped: H2[b][u'-tile w] = tanh(W2 H1^T)*dt; H2[b][127]=dt =
    {
      fx4 c2[2];
      c2[0] = zf; c2[1] = zf;
      __builtin_amdgcn_s_setprio(1);
#pragma unroll
      for (int kk = 0; kk < 4; ++kk) {
        int bro = kk * 64 + hi * 16;
        s16x8 hb0 = *(const s16x8*)(H1 + ho(lo, bro));
        s16x8 hb1 = *(const s16x8*)(H1 + ho(16 + lo, bro));
        c2[0] = __builtin_amdgcn_mfma_f32_16x16x32_bf16(w2r[kk], hb0, c2[0], 0, 0, 0);
        c2[1] = __builtin_amdgcn_mfma_f32_16x16x32_bf16(w2r[kk], hb1, c2[1], 0, 0, 0);
      }
      __builtin_amdgcn_s_setprio(0);
#pragma unroll
      for (int j = 0; j < 2; ++j) {
        float h0 = tanh5(c2[j][0]) * dt2[j];
        float h1x = tanh5(c2[j][1]) * dt2[j];
        float h2x = tanh5(c2[j][2]) * dt2[j];
        float h3 = tanh5(c2[j][3]) * dt2[j];
        if (w == 7 && hi == 3) h3 = dt2[j];        // u' = 127 slot
        uint2 q;
        q.x = cvt_pk_bf16(h0, h1x);
        q.y = cvt_pk_bf16(h2x, h3);
        *(uint2*)(H2 + ho(j * 16 + lo, (16 * w + 4 * hi) * 2)) = q;
      }
    }
    __syncthreads();

    // ===== S3: Yr += W3 H2^T  (b3*dt via col 127) =========================
    __builtin_amdgcn_s_setprio(1);
#pragma unroll
    for (int kk = 0; kk < 4; ++kk) {
      int bro = kk * 64 + hi * 16;
      s16x8 bb0 = *(const s16x8*)(H2 + ho(lo, bro));
      s16x8 bb1 = *(const s16x8*)(H2 + ho(16 + lo, bro));
#pragma unroll
      for (int i = 0; i < 4; ++i) {
        Yr[i][0] = __builtin_amdgcn_mfma_f32_16x16x32_bf16(w3r[i][kk], bb0, Yr[i][0], 0, 0, 0);
        Yr[i][1] = __builtin_amdgcn_mfma_f32_16x16x32_bf16(w3r[i][kk], bb1, Yr[i][1], 0, 0, 0);
      }
    }
    __builtin_amdgcn_s_setprio(0);
    write_yb();
    __syncthreads();
  }

  // ---- final store: coalesced fp32 from bf16 Yb -------------------------
  for (int idx = tid; idx < BM * DD; idx += 512) {
    int b = idx >> 9, d = idx & 511;
    unsigned short hx = *(const unsigned short*)(Yb + ybo(b, 2 * d));
    out[(size_t)(b0 + b) * 513 + d] = bf2f((unsigned int)hx);
  }
}

// ---------------------------------------------------------------------------
// Loss column:  loss = ycum[-2] = 0.01 * sum_{t=1..98} gm_t   (exact algebra)
// ---------------------------------------------------------------------------
__global__ void loss_kernel(const float* __restrict__ bdp,
                            const float* __restrict__ sp,
                            const float* __restrict__ sdp,
                            float* __restrict__ out) {
  int b = blockIdx.x * 256 + threadIdx.x;
  if (b >= NB) return;
  float bd = bdp[b];
  float Kv = sp[b] + __logf(-bd + 0.01f) - __logf(sdp[b] + 0.01f);
  float acc = 0.0f;
  for (int t = 1; t <= 98; ++t) {
    float m = 0.01f * (float)t - 1.0f;     // in (-1, 0)
    float L = __logf(-m);                  // negative
    acc += (-bd) / (m * L) * (Kv - __logf(-L));
  }
  out[(size_t)b * 513 + 512] = 0.01f * acc;
}

// ---------------------------------------------------------------------------
extern "C" void kernel_launch(void* const* d_in, const int* in_sizes, int n_in,
                              void* d_out, int out_size, void* d_ws, size_t ws_size,
                              hipStream_t stream) {
  const float* y0    = (const float*)d_in[0];
  const float* t_seq = (const float*)d_in[1];
  const float* W1    = (const float*)d_in[2];
  const float* b1    = (const float*)d_in[3];
  const float* W2    = (const float*)d_in[4];
  const float* b2    = (const float*)d_in[5];
  const float* W3    = (const float*)d_in[6];
  const float* b3    = (const float*)d_in[7];
  const float* bd    = (const float*)d_in[9];
  const float* s_    = (const float*)d_in[10];
  const float* sd    = (const float*)d_in[11];
  const int*   kptr  = (const int*)d_in[12];
  float* out = (float*)d_out;
  unsigned short* ws = (unsigned short*)d_ws;

  prep_weights<<<576, 256, 0, stream>>>(W1, W2, W3, b2, b3, ws);
  ode_main<<<256, 512, 0, stream>>>(y0, t_seq, b1,
                                    ws, ws + 65536, ws + 81920, kptr, out);
  loss_kernel<<<32, 256, 0, stream>>>(bd, s_, sd, out);
}

// Round 15
// 93.091 us; speedup vs baseline: 1.2043x; 1.0126x over previous
//
#include <hip/hip_runtime.h>

// ---------------------------------------------------------------------------
// STRODE fused kernel for MI355X (gfx950) — round 14 (resubmit; infra flake)
// r13 structure (83 us) + two VALU-sink deletions:
//  1. XOR-swizzle -> +16B row padding (Yb stride 1040 B, H 272 B). Same
//     minimum-aliasing bank behavior (8 lanes / 4-bank group = b128 floor),
//     but LDS addr = lane-const base + IMMEDIATE offset => ds_read_b128
//     offset:N, zero per-access address VALU.
//  2. MFMA via inline asm with "a"-constrained A operands: weights live in
//     AGPRs and are read DIRECTLY by the matrix op (no accvgpr_read copies).
// Everything else identical to r13 (S2-swap, col-127 bias/dt folds, fp32 Yr).
// ---------------------------------------------------------------------------

typedef __attribute__((ext_vector_type(8))) short s16x8;   // 8 x bf16 frag
typedef __attribute__((ext_vector_type(4))) float fx4;     // MFMA acc

#define NB 8192
#define DD 512
#define UU 100
#define UP 128
#define BM 32
#define YSTR 1040                    // 512*2 + 16 pad
#define HSTR 272                     // 128*2 + 16 pad

__device__ __forceinline__ unsigned int f2bf(float x) {
  unsigned int u = __float_as_uint(x);
  return (u + 0x7FFFu + ((u >> 16) & 1u)) >> 16;   // RNE (prep only)
}
__device__ __forceinline__ float bf2f(unsigned int h) {
  return __uint_as_float(h << 16);
}
__device__ __forceinline__ unsigned int cvt_pk_bf16(float lo, float hi) {
  unsigned int r;
  asm("v_cvt_pk_bf16_f32 %0, %1, %2" : "=v"(r) : "v"(lo), "v"(hi));
  return r;
}
__device__ __forceinline__ float tanh5(float x) {
  float e = __builtin_amdgcn_exp2f(x * 2.885390081777927f);
  return 1.0f - 2.0f / (e + 1.0f);
}
// MFMA with A pinned in AGPR (direct read, no copy); B and C/D in VGPR.
__device__ __forceinline__ fx4 mfma_a(s16x8 a, s16x8 b, fx4 c) {
  asm("v_mfma_f32_16x16x32_bf16 %0, %1, %2, %0" : "+v"(c) : "a"(a), "v"(b));
  return c;
}

// ---------------------------------------------------------------------------
// Weight prep: fp32 -> bf16, pad U=100 -> 128 with zeros.
//   W2b col 127 = b2 (pairs with H1[*][127]=1.0)
//   W3b col 127 = b3 (pairs with H2[b][127]=dt[b])
// ---------------------------------------------------------------------------
__global__ void prep_weights(const float* __restrict__ W1,
                             const float* __restrict__ W2,
                             const float* __restrict__ W3,
                             const float* __restrict__ b2,
                             const float* __restrict__ b3,
                             unsigned short* __restrict__ ws) {
  int e = blockIdx.x * 256 + threadIdx.x;
  if (e < 65536) {                        // W1b[128][512]
    int u = e >> 9, kc = e & 511;
    ws[e] = (u < UU) ? (unsigned short)f2bf(W1[u * DD + kc]) : (unsigned short)0;
  } else if (e < 81920) {                 // W2b[128][128]
    int e2 = e - 65536;
    int n = e2 >> 7, kc = e2 & 127;
    unsigned short v = 0;
    if (kc == 127)      v = (n < UU) ? (unsigned short)f2bf(b2[n]) : (unsigned short)0;
    else if (n < UU && kc < UU) v = (unsigned short)f2bf(W2[n * UU + kc]);
    ws[e] = v;
  } else if (e < 147456) {                // W3b[512][128]
    int e3 = e - 81920;
    int d = e3 >> 7, kc = e3 & 127;
    unsigned short v = 0;
    if (kc == 127)      v = (unsigned short)f2bf(b3[d]);
    else if (kc < UU)   v = (unsigned short)f2bf(W3[d * UU + kc]);
    ws[e] = v;
  }
}

// ---------------------------------------------------------------------------
// Main fused ODE kernel. grid = 256 WGs x 512 thr (8 waves), 32 rows/WG.
// ---------------------------------------------------------------------------
__global__ __launch_bounds__(512) __attribute__((amdgpu_waves_per_eu(2, 2)))
void ode_main(
    const float* __restrict__ y0, const float* __restrict__ t_seq,
    const float* __restrict__ b1,
    const unsigned short* __restrict__ W1b,
    const unsigned short* __restrict__ W2b,
    const unsigned short* __restrict__ W3b,
    const int* __restrict__ kptr, float* __restrict__ out) {
  __shared__ char Yb[BM * YSTR];     // 33.3 KB bf16 Y [32][512+pad]
  __shared__ char H1[BM * HSTR];     //  8.7 KB bf16 H1 [32][128+pad]; col127=1
  __shared__ char H2[BM * HSTR];     //  8.7 KB bf16 H2 [32][128+pad]; col127=dt

  const int tid  = threadIdx.x;
  const int w    = tid >> 6;         // wave 0..7
  const int lane = tid & 63;
  const int lo   = lane & 15;
  const int hi   = lane >> 4;
  const int b0   = blockIdx.x * BM;
  const int k    = *kptr;
  const float kinv = 1.0f / (float)k;

  // lane-constant LDS bases (all accesses below use compile-time offsets)
  const int yrb  = lo * YSTR + hi * 16;            // Yb reads (row lo / +16)
  const int ywb  = lo * YSTR + w * 128 + hi * 8;   // Yb writes
  const int hrb  = lo * HSTR + hi * 16;            // H1/H2 reads
  const int hwb  = lo * HSTR + w * 32 + hi * 8;    // H1/H2 writes

  // ---- register-resident weights (pinned to AGPR by mfma_a "a" use) -----
  s16x8 w1r[16];                     // W1[u=16w+lo][K=512]  64 regs
#pragma unroll
  for (int kk = 0; kk < 16; ++kk)
    w1r[kk] = *(const s16x8*)(W1b + (16 * w + lo) * DD + kk * 32 + hi * 8);
  s16x8 w2r[4];                      // W2[u'=16w+lo][K=128] 16 regs
#pragma unroll
  for (int kk = 0; kk < 4; ++kk)
    w2r[kk] = *(const s16x8*)(W2b + (16 * w + lo) * UP + kk * 32 + hi * 8);
  s16x8 w3r[4][4];                   // W3[d=(4w+i)*16+lo][K=128] 64 regs
#pragma unroll
  for (int i = 0; i < 4; ++i)
#pragma unroll
    for (int kk = 0; kk < 4; ++kk)
      w3r[i][kk] = *(const s16x8*)(W3b + ((4 * w + i) * 16 + lo) * UP + kk * 32 + hi * 8);

  // ---- hoisted per-thread constants -------------------------------------
  float b1v[4];                      // u = 16w + 4hi + r
#pragma unroll
  for (int r = 0; r < 4; ++r) {
    int u = 16 * w + 4 * hi + r;
    b1v[r] = (u < UU) ? b1[u] : 0.0f;
  }
  float dt2[2];                      // dt for b = j*16+lo
#pragma unroll
  for (int j = 0; j < 2; ++j) {
    int b = b0 + j * 16 + lo;
    dt2[j] = (t_seq[2 * b + 1] - t_seq[2 * b]) * kinv;
  }

  // ---- persistent Y: Yr[i][j][r] = Y[b=j*16+lo][d=(4w+i)*16+hi*4+r] ------
  fx4 Yr[4][2];
#pragma unroll
  for (int i = 0; i < 4; ++i)
#pragma unroll
    for (int j = 0; j < 2; ++j) {
      const float* p = y0 + (size_t)(b0 + j * 16 + lo) * DD + (4 * w + i) * 16 + hi * 4;
      Yr[i][j] = *(const fx4*)p;
    }

  auto write_yb = [&]() {
#pragma unroll
    for (int i = 0; i < 4; ++i)
#pragma unroll
      for (int j = 0; j < 2; ++j) {
        uint2 q;
        q.x = cvt_pk_bf16(Yr[i][j][0], Yr[i][j][1]);
        q.y = cvt_pk_bf16(Yr[i][j][2], Yr[i][j][3]);
        *(uint2*)(Yb + ywb + i * 32 + j * 16 * YSTR) = q;
      }
  };
  write_yb();
  __syncthreads();

  const fx4 zf = {0.f, 0.f, 0.f, 0.f};

#pragma unroll 1
  for (int s = 0; s < k; ++s) {
    // ===== S1: H1[b][u-tile w] = tanh(W1 Y^T + b1); H1[*][127] = 1.0 ======
    {
      fx4 aA[2], aB[2];
#pragma unroll
      for (int j = 0; j < 2; ++j)
#pragma unroll
        for (int r = 0; r < 4; ++r) { aA[j][r] = b1v[r]; aB[j][r] = 0.0f; }
      __builtin_amdgcn_s_setprio(1);
#pragma unroll
      for (int kk = 0; kk < 16; kk += 2) {
        s16x8 b00 = *(const s16x8*)(Yb + yrb + kk * 64);
        s16x8 b01 = *(const s16x8*)(Yb + yrb + kk * 64 + 16 * YSTR);
        s16x8 b10 = *(const s16x8*)(Yb + yrb + (kk + 1) * 64);
        s16x8 b11 = *(const s16x8*)(Yb + yrb + (kk + 1) * 64 + 16 * YSTR);
        aA[0] = mfma_a(w1r[kk], b00, aA[0]);
        aA[1] = mfma_a(w1r[kk], b01, aA[1]);
        aB[0] = mfma_a(w1r[kk + 1], b10, aB[0]);
        aB[1] = mfma_a(w1r[kk + 1], b11, aB[1]);
      }
      __builtin_amdgcn_s_setprio(0);
#pragma unroll
      for (int j = 0; j < 2; ++j) {
        float v0 = tanh5(aA[j][0] + aB[j][0]);
        float v1 = tanh5(aA[j][1] + aB[j][1]);
        float v2 = tanh5(aA[j][2] + aB[j][2]);
        float v3 = tanh5(aA[j][3] + aB[j][3]);
        if (w == 7 && hi == 3) v3 = 1.0f;          // u = 127 slot
        uint2 q;
        q.x = cvt_pk_bf16(v0, v1);
        q.y = cvt_pk_bf16(v2, v3);
        *(uint2*)(H1 + hwb + j * 16 * HSTR) = q;
      }
    }
    __syncthreads();

    // ===== S2 swapped: H2[b][u'-tile w] = tanh(W2 H1^T)*dt; H2[b][127]=dt =
    {
      fx4 c2[2];
      c2[0] = zf; c2[1] = zf;
      __builtin_amdgcn_s_setprio(1);
#pragma unroll
      for (int kk = 0; kk < 4; ++kk) {
        s16x8 hb0 = *(const s16x8*)(H1 + hrb + kk * 64);
        s16x8 hb1 = *(const s16x8*)(H1 + hrb + kk * 64 + 16 * HSTR);
        c2[0] = mfma_a(w2r[kk], hb0, c2[0]);
        c2[1] = mfma_a(w2r[kk], hb1, c2[1]);
      }
      __builtin_amdgcn_s_setprio(0);
#pragma unroll
      for (int j = 0; j < 2; ++j) {
        float h0 = tanh5(c2[j][0]) * dt2[j];
        float h1x = tanh5(c2[j][1]) * dt2[j];
        float h2x = tanh5(c2[j][2]) * dt2[j];
        float h3 = tanh5(c2[j][3]) * dt2[j];
        if (w == 7 && hi == 3) h3 = dt2[j];        // u' = 127 slot
        uint2 q;
        q.x = cvt_pk_bf16(h0, h1x);
        q.y = cvt_pk_bf16(h2x, h3);
        *(uint2*)(H2 + hwb + j * 16 * HSTR) = q;
      }
    }
    __syncthreads();

    // ===== S3: Yr += W3 H2^T  (b3*dt via col 127) =========================
    __builtin_amdgcn_s_setprio(1);
#pragma unroll
    for (int kk = 0; kk < 4; ++kk) {
      s16x8 bb0 = *(const s16x8*)(H2 + hrb + kk * 64);
      s16x8 bb1 = *(const s16x8*)(H2 + hrb + kk * 64 + 16 * HSTR);
#pragma unroll
      for (int i = 0; i < 4; ++i) {
        Yr[i][0] = mfma_a(w3r[i][kk], bb0, Yr[i][0]);
        Yr[i][1] = mfma_a(w3r[i][kk], bb1, Yr[i][1]);
      }
    }
    __builtin_amdgcn_s_setprio(0);
    write_yb();
    __syncthreads();
  }

  // ---- final store: coalesced fp32 from bf16 Yb -------------------------
  for (int idx = tid; idx < BM * DD; idx += 512) {
    int b = idx >> 9, d = idx & 511;
    unsigned short hx = *(const unsigned short*)(Yb + b * YSTR + 2 * d);
    out[(size_t)(b0 + b) * 513 + d] = bf2f((unsigned int)hx);
  }
}

// ---------------------------------------------------------------------------
// Loss column:  loss = ycum[-2] = 0.01 * sum_{t=1..98} gm_t   (exact algebra)
// ---------------------------------------------------------------------------
__global__ void loss_kernel(const float* __restrict__ bdp,
                            const float* __restrict__ sp,
                            const float* __restrict__ sdp,
                            float* __restrict__ out) {
  int b = blockIdx.x * 256 + threadIdx.x;
  if (b >= NB) return;
  float bd = bdp[b];
  float Kv = sp[b] + __logf(-bd + 0.01f) - __logf(sdp[b] + 0.01f);
  float acc = 0.0f;
  for (int t = 1; t <= 98; ++t) {
    float m = 0.01f * (float)t - 1.0f;     // in (-1, 0)
    float L = __logf(-m);                  // negative
    acc += (-bd) / (m * L) * (Kv - __logf(-L));
  }
  out[(size_t)b * 513 + 512] = 0.01f * acc;
}

// ---------------------------------------------------------------------------
extern "C" void kernel_launch(void* const* d_in, const int* in_sizes, int n_in,
                              void* d_out, int out_size, void* d_ws, size_t ws_size,
                              hipStream_t stream) {
  const float* y0    = (const float*)d_in[0];
  const float* t_seq = (const float*)d_in[1];
  const float* W1    = (const float*)d_in[2];
  const float* b1    = (const float*)d_in[3];
  const float* W2    = (const float*)d_in[4];
  const float* b2    = (const float*)d_in[5];
  const float* W3    = (const float*)d_in[6];
  const float* b3    = (const float*)d_in[7];
  const float* bd    = (const float*)d_in[9];
  const float* s_    = (const float*)d_in[10];
  const float* sd    = (const float*)d_in[11];
  const int*   kptr  = (const int*)d_in[12];
  float* out = (float*)d_out;
  unsigned short* ws = (unsigned short*)d_ws;

  prep_weights<<<576, 256, 0, stream>>>(W1, W2, W3, b2, b3, ws);
  ode_main<<<256, 512, 0, stream>>>(y0, t_seq, b1,
                                    ws, ws + 65536, ws + 81920, kptr, out);
  loss_kernel<<<32, 256, 0, stream>>>(bd, s_, sd, out);
}